// Round 21
// baseline (104.416 us; speedup 1.0000x reference)
//
#include <hip/hip_runtime.h>

#define D 64
#define BM 256        // queries per block (8 waves: 4 wm x 2 wn)
#define NCHUNK 8      // K split across blocks
#define NLIST (2 * NCHUNK)   // union-top-2 per chunk
#define DECAYF 0.8f
#define OMDF 0.2f
#define EPSF 1e-5f

typedef _Float16 f16;
typedef _Float16 f16x8 __attribute__((ext_vector_type(8)));
typedef float f32x4 __attribute__((ext_vector_type(4)));

// ---------- prep: frag-major f16 split (hi only) + e2 + sum(cluster_size) + zero-init ----
__global__ __launch_bounds__(512) void prep_kernel(
    const float* __restrict__ emb, const float* __restrict__ cluster_size,
    f16* __restrict__ eh2, float* __restrict__ e2,
    float* __restrict__ cs_sum, float* __restrict__ ncs, float* __restrict__ nea,
    int K)
{
    __shared__ float red[512];
    int t = blockIdx.x * 512 + threadIdx.x;
    int lane = t & 63;
    int sub  = (t >> 6) & 7;
    int tile = t >> 9;
    int wn = sub >> 2, nf = (sub >> 1) & 1, ks = sub & 1;
    int lrow = lane & 15, lkg = lane >> 4;
    int k  = tile * 64 + wn * 32 + nf * 16 + lrow;
    int d0 = ks * 32 + lkg * 8;

    // zero accumulation targets (stream order guarantees zero-before-atomics)
    {
        float4 z = {0.f, 0.f, 0.f, 0.f};
        float4* nea4 = reinterpret_cast<float4*>(nea);
        nea4[t]         = z;
        nea4[t + 65536] = z;
        if (t < 2048) reinterpret_cast<float4*>(ncs)[t] = z;
    }

    const float4* p = reinterpret_cast<const float4*>(emb + (size_t)k * D + d0);
    float4 a = p[0], b = p[1];
    float v[8] = {a.x, a.y, a.z, a.w, b.x, b.y, b.z, b.w};
    union { f16 h[8]; uint4 u; } H;
    float part = 0.f;
#pragma unroll
    for (int j = 0; j < 8; ++j) {
        part = fmaf(v[j], v[j], part);
        H.h[j] = (f16)v[j];
    }
    reinterpret_cast<uint4*>(eh2)[t] = H.u;

    red[threadIdx.x] = part;

    if (blockIdx.x < (K >> 9)) {
        float cv = cluster_size[t];
#pragma unroll
        for (int m = 1; m < 64; m <<= 1) cv += __shfl_xor(cv, m, 64);
        if ((threadIdx.x & 63) == 0) atomicAdd(cs_sum, cv);
    }
    __syncthreads();

    if (threadIdx.x < 64) {
        int r = threadIdx.x;
        int rwn = r >> 5, rnf = (r >> 4) & 1, rlr = r & 15;
        float s = 0.f;
#pragma unroll
        for (int kks = 0; kks < 2; ++kks)
#pragma unroll
            for (int g = 0; g < 4; ++g)
                s += red[((rwn * 2 + rnf) * 2 + kks) * 64 + g * 16 + rlr];
        e2[tile * 64 + r] = s;
    }
}

// ---------- MFMA 1-pass f16 capture + top-2, union-merged across wn via LDS ----------
// 8-wave blocks (4 wm x 2 wn): doubles waves/CU if residency was block-slot-capped.
__global__ __launch_bounds__(512, 4) void argmin_kernel(
    const float* __restrict__ x, const f16* __restrict__ eh2,
    const float* __restrict__ e2, int* __restrict__ pidx, int n, int K)
{
    __shared__ float se2a[1024];          // whole-chunk +0.5*e2 (4KB)
    __shared__ uint4 smerge[4][16][4][2]; // [wm][s][lkg][wn] = {u1, id1, u2, id2} (8KB)

    const int tx   = threadIdx.x;
    const int lane = tx & 63;
    const int wid  = tx >> 6;            // 0..7
    const int wm   = wid >> 1, wn = wid & 1;   // wm 0..3
    const int lrow = lane & 15;
    const int lkg  = lane >> 4;

    const int chunk = blockIdx.x % NCHUNK;
    const int mblk  = blockIdx.x / NCHUNK;
    const int q0    = mblk * BM;
    const int kc    = K / NCHUNK;    // 1024
    const int k0    = chunk * kc;
    const int gt0   = chunk * (kc / 64);
    const int NT    = kc / 64;       // 16 tiles of 64 codes

    // ---- A fragments (NEGATED f16 hi) + 0.5*f2 per slot ----
    f16x8 ah[4][2];
    f32x4 hf2[4];
#pragma unroll
    for (int m = 0; m < 4; ++m) {
        float f2part = 0.f;
#pragma unroll
        for (int ks = 0; ks < 2; ++ks) {
            int row = q0 + wm * 64 + m * 16 + lrow;
            const float4* p = reinterpret_cast<const float4*>(
                x + (size_t)row * D + ks * 32 + lkg * 8);
            float4 va = p[0], vb = p[1];
            float t[8] = {va.x, va.y, va.z, va.w, vb.x, vb.y, vb.z, vb.w};
#pragma unroll
            for (int j = 0; j < 8; ++j) {
                f2part = fmaf(t[j], t[j], f2part);
                ah[m][ks][j] = (f16)(-t[j]);
            }
        }
        f2part += __shfl_xor(f2part, 16, 64);
        f2part += __shfl_xor(f2part, 32, 64);
#pragma unroll
        for (int r = 0; r < 4; ++r)
            hf2[m][r] = 0.5f * __shfl(f2part, lkg * 4 + r, 64);
    }

    // ---- whole-chunk e2 table, prescaled by +0.5 ----
    for (int i = tx; i < kc; i += 512) se2a[i] = 0.5f * e2[k0 + i];
    __syncthreads();

    // ---- packed top-2 (sorted p1<=p2) per C-slot ----
    unsigned int p1[16], p2[16];
#pragma unroll
    for (int s = 0; s < 16; ++s) { p1[s] = 0xFFFFFFFFu; p2[s] = 0xFFFFFFFFu; }

    auto LOADB = [&](f16x8 (&BH)[2][2], int ttv) {
        const f16* bhb = eh2 + ((size_t)(gt0 + ttv) << 12);
#pragma unroll
        for (int nf = 0; nf < 2; ++nf)
#pragma unroll
            for (int ks = 0; ks < 2; ++ks) {
                int sub = (wn * 2 + nf) * 2 + ks;
                BH[nf][ks] = *reinterpret_cast<const f16x8*>(bhb + sub * 512 + lane * 8);
            }
    };

    auto COMPUTE = [&](const f16x8 (&BH)[2][2], int ttv) {
        const float he0 = se2a[ttv * 64 + wn * 32 + lrow];
        const float he1 = se2a[ttv * 64 + wn * 32 + 16 + lrow];
        const unsigned int tagA = (unsigned int)(ttv * 2);
        const unsigned int tagB = tagA + 1u;
#pragma unroll
        for (int m = 0; m < 4; ++m) {
            f32x4 hh0 = hf2[m] + he0;
            f32x4 hh1 = hf2[m] + he1;
            __builtin_amdgcn_s_setprio(1);
            hh0 = __builtin_amdgcn_mfma_f32_16x16x32_f16(ah[m][0], BH[0][0], hh0, 0, 0, 0);
            hh1 = __builtin_amdgcn_mfma_f32_16x16x32_f16(ah[m][0], BH[1][0], hh1, 0, 0, 0);
            hh0 = __builtin_amdgcn_mfma_f32_16x16x32_f16(ah[m][1], BH[0][1], hh0, 0, 0, 0);
            hh1 = __builtin_amdgcn_mfma_f32_16x16x32_f16(ah[m][1], BH[1][1], hh1, 0, 0, 0);
            __builtin_amdgcn_s_setprio(0);
#pragma unroll
            for (int r = 0; r < 4; ++r) {
                unsigned int uA = (__float_as_uint(hh0[r]) & 0xFFFFFFE0u) | tagA;
                unsigned int uB = (__float_as_uint(hh1[r]) & 0xFFFFFFE0u) | tagB;
                unsigned int lo = uA < uB ? uA : uB;
                unsigned int hi = uA < uB ? uB : uA;
                int s = m * 4 + r;
                unsigned int t1 = p1[s], t2 = p2[s];
                unsigned int mx = t1 > lo ? t1 : lo;
                unsigned int mn2 = t2 < hi ? t2 : hi;
                p1[s] = t1 < lo ? t1 : lo;
                p2[s] = mx < mn2 ? mx : mn2;
            }
        }
    };

    // ---- 2-stage register pipeline: load(t+1) overlaps compute(t) ----
    f16x8 bh[2][2], nh[2][2];
    LOADB(bh, 0);
#pragma unroll 1
    for (int tt = 0; tt < NT; tt += 2) {
        LOADB(nh, tt + 1);               // NT even: tt+1 < NT always
        COMPUTE(bh, tt);
        if (tt + 2 < NT) LOADB(bh, tt + 2);
        COMPUTE(nh, tt + 1);
    }

    // ---- cross-lane top-2 merge over the 16 col-lanes; stash to LDS ----
#pragma unroll
    for (int s = 0; s < 16; ++s) {
        unsigned int u1 = p1[s], u2 = p2[s];
        unsigned int tg1 = u1 & 31u, tg2 = u2 & 31u;
        int c1 = (int)((tg1 >> 1) << 6) | (int)((tg1 & 1u) << 4) | (wn << 5) | lrow;
        int c2 = (int)((tg2 >> 1) << 6) | (int)((tg2 & 1u) << 4) | (wn << 5) | lrow;
#pragma unroll
        for (int xm = 1; xm < 16; xm <<= 1) {
            unsigned int o1 = __shfl_xor(u1, xm, 64);
            unsigned int o2 = __shfl_xor(u2, xm, 64);
            int oc1 = __shfl_xor(c1, xm, 64);
            int oc2 = __shfl_xor(c2, xm, 64);
            bool a = o1 < u1 || (o1 == u1 && oc1 < c1);
            unsigned int w1 = a ? o1 : u1;  int wc1 = a ? oc1 : c1;
            unsigned int l1 = a ? u1 : o1;  int lc1 = a ? c1 : oc1;
            bool b = o2 < u2 || (o2 == u2 && oc2 < c2);
            unsigned int m2 = b ? o2 : u2;  int mc2 = b ? oc2 : c2;
            bool cgt = m2 < l1 || (m2 == l1 && mc2 < lc1);
            u1 = w1; c1 = wc1;
            u2 = cgt ? m2 : l1; c2 = cgt ? mc2 : lc1;
        }
        if (lrow == 0) {
            uint4 rec;
            rec.x = u1; rec.y = (unsigned int)(k0 + c1);
            rec.z = u2; rec.w = (unsigned int)(k0 + c2);
            smerge[wm][s][lkg][wn] = rec;
        }
    }
    __syncthreads();

    // ---- union-merge the two wn halves (exact top-2 of the chunk) ----
    if (wn == 0 && lrow == 0) {
#pragma unroll
        for (int s = 0; s < 16; ++s) {
            uint4 A = smerge[wm][s][lkg][0];
            uint4 B = smerge[wm][s][lkg][1];
            bool afirst = A.x < B.x || (A.x == B.x && A.y < B.y);
            unsigned int w1i = afirst ? A.y : B.y;
            unsigned int sAu = afirst ? A.z : B.z;  unsigned int sAi = afirst ? A.w : B.w;
            unsigned int sBu = afirst ? B.x : A.x;  unsigned int sBi = afirst ? B.y : A.y;
            bool c2nd = sAu < sBu || (sAu == sBu && sAi < sBi);
            unsigned int w2i = c2nd ? sAi : sBi;
            int m = s >> 2, r = s & 3;
            int row = q0 + wm * 64 + m * 16 + lkg * 4 + r;
            pidx[(size_t)(chunk * 2)     * n + row] = (int)w1i;
            pidx[(size_t)(chunk * 2 + 1) * n + row] = (int)w2i;
        }
    }
}

// ---------- fused exact re-rank + quantize + scatter: wave/query, 4 lanes/candidate ----
__global__ __launch_bounds__(256) void rerank_kernel(
    const float* __restrict__ x, const float* __restrict__ emb, const float* __restrict__ e2,
    const int* __restrict__ pidx, float* __restrict__ out_ind, float* __restrict__ quant,
    float* __restrict__ embed_sum, float* __restrict__ counts, int n)
{
    int gid  = blockIdx.x * blockDim.x + threadIdx.x;
    int q    = gid >> 6;
    int lane = gid & 63;
    int c    = lane >> 2;
    int j    = lane & 3;
    if (q >= n) return;

    int k = pidx[(size_t)c * n + q];
    const float4* ep = reinterpret_cast<const float4*>(emb + (size_t)k * D);
    const float4* xp = reinterpret_cast<const float4*>(x + (size_t)q * D);

    float a0 = 0.f, a1 = 0.f, a2 = 0.f, a3 = 0.f;
#pragma unroll
    for (int i = 0; i < 4; ++i) {
        float4 e4 = ep[j + 4 * i];          // contiguous 64B per candidate
        float4 x4 = xp[j + 4 * i];
        a0 = fmaf(x4.x, e4.x, a0);
        a1 = fmaf(x4.y, e4.y, a1);
        a2 = fmaf(x4.z, e4.z, a2);
        a3 = fmaf(x4.w, e4.w, a3);
    }
    float p = (a0 + a1) + (a2 + a3);
    p += __shfl_xor(p, 1, 64);
    p += __shfl_xor(p, 2, 64);
    float dist = fmaf(p, -2.0f, e2[k]);
    int   bk   = k;

#pragma unroll
    for (int xm = 4; xm < 64; xm <<= 1) {
        float od = __shfl_xor(dist, xm, 64);
        int   ok = __shfl_xor(bk, xm, 64);
        if (od < dist || (od == dist && ok < bk)) { dist = od; bk = ok; }
    }

    float xv = x[(size_t)q * D + lane];
    quant[(size_t)q * D + lane] = emb[(size_t)bk * D + lane];
    atomicAdd(embed_sum + (size_t)bk * D + lane, xv);
    if (lane == 0) {
        out_ind[q] = (float)bk;
        atomicAdd(counts + bk, 1.0f);
    }
}

// ---------- single fused EMA: cluster_size + embed_avg + normalize ----------
__global__ __launch_bounds__(256) void ema_kernel(
    const float* __restrict__ cluster_size, const float* __restrict__ embed_avg,
    const float* __restrict__ cs_sum, float* __restrict__ ncs,
    float* __restrict__ nea, float* __restrict__ enorm, int K, int n)
{
    int gid = blockIdx.x * blockDim.x + threadIdx.x;
    if (gid >= K * D) return;
    int k = gid >> 6;
    float total = DECAYF * cs_sum[0] + OMDF * (float)n;
    float cnew  = cluster_size[k] * DECAYF + ncs[k] * OMDF;
    if ((gid & 63) == 0) ncs[k] = cnew;
    float v = embed_avg[gid] * DECAYF + nea[gid] * OMDF;
    nea[gid] = v;
    float smoothed = (cnew + EPSF) / (total + (float)K * EPSF) * total;
    enorm[gid] = v / smoothed;
}

extern "C" void kernel_launch(void* const* d_in, const int* in_sizes, int n_in,
                              void* d_out, int out_size, void* d_ws, size_t ws_size,
                              hipStream_t stream) {
    const float* x            = (const float*)d_in[0];   // [n, 64]
    const float* emb          = (const float*)d_in[1];   // [K, 64]
    const float* cluster_size = (const float*)d_in[2];   // [K]
    const float* embed_avg    = (const float*)d_in[3];   // [K, 64]

    const int n = in_sizes[0] / D;   // 16384
    const int K = in_sizes[1] / D;   // 8192

    // output layout (fp32): quantize | embed_ind | embed_normalized | new_cluster_size | new_embed_avg
    float* out     = (float*)d_out;
    float* quant   = out;                        // n*D
    float* out_ind = quant + (size_t)n * D;      // n
    float* enorm   = out_ind + n;                // K*D  (scratch for eh2 until ema)
    float* ncs     = enorm + (size_t)K * D;      // K    (counts, then EMA'd in place)
    float* nea     = ncs + K;                    // K*D  (embed_sum, then EMA'd in place)

    f16* eh2 = reinterpret_cast<f16*>(enorm);    // K*D f16, fragment-major

    // workspace: e2 | pidx[NLIST][n] | cs_sum
    float* e2     = (float*)d_ws;                        // K
    int*   pidx   = (int*)(e2 + K);                      // NLIST*n
    float* cs_sum = (float*)(pidx + (size_t)NLIST * n);  // 1

    hipMemsetAsync(cs_sum, 0, sizeof(float), stream);

    prep_kernel<<<K * 8 / 512, 512, 0, stream>>>(
        emb, cluster_size, eh2, e2, cs_sum, ncs, nea, K);
    argmin_kernel<<<(n / BM) * NCHUNK, 512, 0, stream>>>(x, eh2, e2, pidx, n, K);
    rerank_kernel<<<(n * 64 + 255) / 256, 256, 0, stream>>>(
        x, emb, e2, pidx, out_ind, quant, nea, ncs, n);
    ema_kernel<<<(K * D + 255) / 256, 256, 0, stream>>>(
        cluster_size, embed_avg, cs_sum, ncs, nea, enorm, K, n);
}

// Round 22
// 88.461 us; speedup vs baseline: 1.1804x; 1.1804x over previous
//
#include <hip/hip_runtime.h>

#define D 64
#define BM 256        // queries per block (8 waves: 4 wm x 2 wn)
#define NCHUNK 8      // K split across blocks
#define NLIST (2 * NCHUNK)   // union-top-2 per chunk
#define DECAYF 0.8f
#define OMDF 0.2f
#define EPSF 1e-5f

typedef _Float16 f16;
typedef _Float16 f16x8 __attribute__((ext_vector_type(8)));
typedef float f32x4 __attribute__((ext_vector_type(4)));

// ---------- prep: frag-major f16 split (hi only) + e2 + sum(cluster_size) + zero-init ----
__global__ __launch_bounds__(512) void prep_kernel(
    const float* __restrict__ emb, const float* __restrict__ cluster_size,
    f16* __restrict__ eh2, float* __restrict__ e2,
    float* __restrict__ cs_sum, float* __restrict__ ncs, float* __restrict__ nea,
    int K)
{
    __shared__ float red[512];
    int t = blockIdx.x * 512 + threadIdx.x;
    int lane = t & 63;
    int sub  = (t >> 6) & 7;
    int tile = t >> 9;
    int wn = sub >> 2, nf = (sub >> 1) & 1, ks = sub & 1;
    int lrow = lane & 15, lkg = lane >> 4;
    int k  = tile * 64 + wn * 32 + nf * 16 + lrow;
    int d0 = ks * 32 + lkg * 8;

    // zero accumulation targets (stream order guarantees zero-before-atomics)
    {
        float4 z = {0.f, 0.f, 0.f, 0.f};
        float4* nea4 = reinterpret_cast<float4*>(nea);
        nea4[t]         = z;
        nea4[t + 65536] = z;
        if (t < 2048) reinterpret_cast<float4*>(ncs)[t] = z;
    }

    const float4* p = reinterpret_cast<const float4*>(emb + (size_t)k * D + d0);
    float4 a = p[0], b = p[1];
    float v[8] = {a.x, a.y, a.z, a.w, b.x, b.y, b.z, b.w};
    union { f16 h[8]; uint4 u; } H;
    float part = 0.f;
#pragma unroll
    for (int j = 0; j < 8; ++j) {
        part = fmaf(v[j], v[j], part);
        H.h[j] = (f16)v[j];
    }
    reinterpret_cast<uint4*>(eh2)[t] = H.u;

    red[threadIdx.x] = part;

    if (blockIdx.x < (K >> 9)) {
        float cv = cluster_size[t];
#pragma unroll
        for (int m = 1; m < 64; m <<= 1) cv += __shfl_xor(cv, m, 64);
        if ((threadIdx.x & 63) == 0) atomicAdd(cs_sum, cv);
    }
    __syncthreads();

    if (threadIdx.x < 64) {
        int r = threadIdx.x;
        int rwn = r >> 5, rnf = (r >> 4) & 1, rlr = r & 15;
        float s = 0.f;
#pragma unroll
        for (int kks = 0; kks < 2; ++kks)
#pragma unroll
            for (int g = 0; g < 4; ++g)
                s += red[((rwn * 2 + rnf) * 2 + kks) * 64 + g * 16 + rlr];
        e2[tile * 64 + r] = s;
    }
}

// ---------- MFMA 1-pass f16 capture + top-2, union-merged across wn via LDS ----------
// 8-wave blocks (4 wm x 2 wn) double residency (r21: occ 23->39%). NO min-waves
// constraint: the (512,4) cap forced VGPR 64 < ~80 needed -> spills (r21 lesson).
__global__ __launch_bounds__(512) void argmin_kernel(
    const float* __restrict__ x, const f16* __restrict__ eh2,
    const float* __restrict__ e2, int* __restrict__ pidx, int n, int K)
{
    __shared__ float se2a[1024];          // whole-chunk +0.5*e2 (4KB)
    __shared__ uint4 smerge[4][16][4][2]; // [wm][s][lkg][wn] = {u1, id1, u2, id2} (8KB)

    const int tx   = threadIdx.x;
    const int lane = tx & 63;
    const int wid  = tx >> 6;            // 0..7
    const int wm   = wid >> 1, wn = wid & 1;   // wm 0..3
    const int lrow = lane & 15;
    const int lkg  = lane >> 4;

    const int chunk = blockIdx.x % NCHUNK;
    const int mblk  = blockIdx.x / NCHUNK;
    const int q0    = mblk * BM;
    const int kc    = K / NCHUNK;    // 1024
    const int k0    = chunk * kc;
    const int gt0   = chunk * (kc / 64);
    const int NT    = kc / 64;       // 16 tiles of 64 codes

    // ---- A fragments (NEGATED f16 hi) + 0.5*f2 per slot ----
    f16x8 ah[4][2];
    f32x4 hf2[4];
#pragma unroll
    for (int m = 0; m < 4; ++m) {
        float f2part = 0.f;
#pragma unroll
        for (int ks = 0; ks < 2; ++ks) {
            int row = q0 + wm * 64 + m * 16 + lrow;
            const float4* p = reinterpret_cast<const float4*>(
                x + (size_t)row * D + ks * 32 + lkg * 8);
            float4 va = p[0], vb = p[1];
            float t[8] = {va.x, va.y, va.z, va.w, vb.x, vb.y, vb.z, vb.w};
#pragma unroll
            for (int j = 0; j < 8; ++j) {
                f2part = fmaf(t[j], t[j], f2part);
                ah[m][ks][j] = (f16)(-t[j]);
            }
        }
        f2part += __shfl_xor(f2part, 16, 64);
        f2part += __shfl_xor(f2part, 32, 64);
#pragma unroll
        for (int r = 0; r < 4; ++r)
            hf2[m][r] = 0.5f * __shfl(f2part, lkg * 4 + r, 64);
    }

    // ---- whole-chunk e2 table, prescaled by +0.5 ----
    for (int i = tx; i < kc; i += 512) se2a[i] = 0.5f * e2[k0 + i];
    __syncthreads();

    // ---- packed top-2 (sorted p1<=p2) per C-slot ----
    unsigned int p1[16], p2[16];
#pragma unroll
    for (int s = 0; s < 16; ++s) { p1[s] = 0xFFFFFFFFu; p2[s] = 0xFFFFFFFFu; }

    auto LOADB = [&](f16x8 (&BH)[2][2], int ttv) {
        const f16* bhb = eh2 + ((size_t)(gt0 + ttv) << 12);
#pragma unroll
        for (int nf = 0; nf < 2; ++nf)
#pragma unroll
            for (int ks = 0; ks < 2; ++ks) {
                int sub = (wn * 2 + nf) * 2 + ks;
                BH[nf][ks] = *reinterpret_cast<const f16x8*>(bhb + sub * 512 + lane * 8);
            }
    };

    auto COMPUTE = [&](const f16x8 (&BH)[2][2], int ttv) {
        const float he0 = se2a[ttv * 64 + wn * 32 + lrow];
        const float he1 = se2a[ttv * 64 + wn * 32 + 16 + lrow];
        const unsigned int tagA = (unsigned int)(ttv * 2);
        const unsigned int tagB = tagA + 1u;
#pragma unroll
        for (int m = 0; m < 4; ++m) {
            f32x4 hh0 = hf2[m] + he0;
            f32x4 hh1 = hf2[m] + he1;
            __builtin_amdgcn_s_setprio(1);
            hh0 = __builtin_amdgcn_mfma_f32_16x16x32_f16(ah[m][0], BH[0][0], hh0, 0, 0, 0);
            hh1 = __builtin_amdgcn_mfma_f32_16x16x32_f16(ah[m][0], BH[1][0], hh1, 0, 0, 0);
            hh0 = __builtin_amdgcn_mfma_f32_16x16x32_f16(ah[m][1], BH[0][1], hh0, 0, 0, 0);
            hh1 = __builtin_amdgcn_mfma_f32_16x16x32_f16(ah[m][1], BH[1][1], hh1, 0, 0, 0);
            __builtin_amdgcn_s_setprio(0);
#pragma unroll
            for (int r = 0; r < 4; ++r) {
                unsigned int uA = (__float_as_uint(hh0[r]) & 0xFFFFFFE0u) | tagA;
                unsigned int uB = (__float_as_uint(hh1[r]) & 0xFFFFFFE0u) | tagB;
                unsigned int lo = uA < uB ? uA : uB;
                unsigned int hi = uA < uB ? uB : uA;
                int s = m * 4 + r;
                unsigned int t1 = p1[s], t2 = p2[s];
                unsigned int mx = t1 > lo ? t1 : lo;
                unsigned int mn2 = t2 < hi ? t2 : hi;
                p1[s] = t1 < lo ? t1 : lo;
                p2[s] = mx < mn2 ? mx : mn2;
            }
        }
    };

    // ---- 2-stage register pipeline: load(t+1) overlaps compute(t) ----
    f16x8 bh[2][2], nh[2][2];
    LOADB(bh, 0);
#pragma unroll 1
    for (int tt = 0; tt < NT; tt += 2) {
        LOADB(nh, tt + 1);               // NT even: tt+1 < NT always
        COMPUTE(bh, tt);
        if (tt + 2 < NT) LOADB(bh, tt + 2);
        COMPUTE(nh, tt + 1);
    }

    // ---- cross-lane top-2 merge over the 16 col-lanes; stash to LDS ----
#pragma unroll
    for (int s = 0; s < 16; ++s) {
        unsigned int u1 = p1[s], u2 = p2[s];
        unsigned int tg1 = u1 & 31u, tg2 = u2 & 31u;
        int c1 = (int)((tg1 >> 1) << 6) | (int)((tg1 & 1u) << 4) | (wn << 5) | lrow;
        int c2 = (int)((tg2 >> 1) << 6) | (int)((tg2 & 1u) << 4) | (wn << 5) | lrow;
#pragma unroll
        for (int xm = 1; xm < 16; xm <<= 1) {
            unsigned int o1 = __shfl_xor(u1, xm, 64);
            unsigned int o2 = __shfl_xor(u2, xm, 64);
            int oc1 = __shfl_xor(c1, xm, 64);
            int oc2 = __shfl_xor(c2, xm, 64);
            bool a = o1 < u1 || (o1 == u1 && oc1 < c1);
            unsigned int w1 = a ? o1 : u1;  int wc1 = a ? oc1 : c1;
            unsigned int l1 = a ? u1 : o1;  int lc1 = a ? c1 : oc1;
            bool b = o2 < u2 || (o2 == u2 && oc2 < c2);
            unsigned int m2 = b ? o2 : u2;  int mc2 = b ? oc2 : c2;
            bool cgt = m2 < l1 || (m2 == l1 && mc2 < lc1);
            u1 = w1; c1 = wc1;
            u2 = cgt ? m2 : l1; c2 = cgt ? mc2 : lc1;
        }
        if (lrow == 0) {
            uint4 rec;
            rec.x = u1; rec.y = (unsigned int)(k0 + c1);
            rec.z = u2; rec.w = (unsigned int)(k0 + c2);
            smerge[wm][s][lkg][wn] = rec;
        }
    }
    __syncthreads();

    // ---- union-merge the two wn halves (exact top-2 of the chunk) ----
    if (wn == 0 && lrow == 0) {
#pragma unroll
        for (int s = 0; s < 16; ++s) {
            uint4 A = smerge[wm][s][lkg][0];
            uint4 B = smerge[wm][s][lkg][1];
            bool afirst = A.x < B.x || (A.x == B.x && A.y < B.y);
            unsigned int w1i = afirst ? A.y : B.y;
            unsigned int sAu = afirst ? A.z : B.z;  unsigned int sAi = afirst ? A.w : B.w;
            unsigned int sBu = afirst ? B.x : A.x;  unsigned int sBi = afirst ? B.y : A.y;
            bool c2nd = sAu < sBu || (sAu == sBu && sAi < sBi);
            unsigned int w2i = c2nd ? sAi : sBi;
            int m = s >> 2, r = s & 3;
            int row = q0 + wm * 64 + m * 16 + lkg * 4 + r;
            pidx[(size_t)(chunk * 2)     * n + row] = (int)w1i;
            pidx[(size_t)(chunk * 2 + 1) * n + row] = (int)w2i;
        }
    }
}

// ---------- fused exact re-rank + quantize + scatter: wave/query, 4 lanes/candidate ----
__global__ __launch_bounds__(256) void rerank_kernel(
    const float* __restrict__ x, const float* __restrict__ emb, const float* __restrict__ e2,
    const int* __restrict__ pidx, float* __restrict__ out_ind, float* __restrict__ quant,
    float* __restrict__ embed_sum, float* __restrict__ counts, int n)
{
    int gid  = blockIdx.x * blockDim.x + threadIdx.x;
    int q    = gid >> 6;
    int lane = gid & 63;
    int c    = lane >> 2;
    int j    = lane & 3;
    if (q >= n) return;

    int k = pidx[(size_t)c * n + q];
    const float4* ep = reinterpret_cast<const float4*>(emb + (size_t)k * D);
    const float4* xp = reinterpret_cast<const float4*>(x + (size_t)q * D);

    float a0 = 0.f, a1 = 0.f, a2 = 0.f, a3 = 0.f;
#pragma unroll
    for (int i = 0; i < 4; ++i) {
        float4 e4 = ep[j + 4 * i];          // contiguous 64B per candidate
        float4 x4 = xp[j + 4 * i];
        a0 = fmaf(x4.x, e4.x, a0);
        a1 = fmaf(x4.y, e4.y, a1);
        a2 = fmaf(x4.z, e4.z, a2);
        a3 = fmaf(x4.w, e4.w, a3);
    }
    float p = (a0 + a1) + (a2 + a3);
    p += __shfl_xor(p, 1, 64);
    p += __shfl_xor(p, 2, 64);
    float dist = fmaf(p, -2.0f, e2[k]);
    int   bk   = k;

#pragma unroll
    for (int xm = 4; xm < 64; xm <<= 1) {
        float od = __shfl_xor(dist, xm, 64);
        int   ok = __shfl_xor(bk, xm, 64);
        if (od < dist || (od == dist && ok < bk)) { dist = od; bk = ok; }
    }

    float xv = x[(size_t)q * D + lane];
    quant[(size_t)q * D + lane] = emb[(size_t)bk * D + lane];
    atomicAdd(embed_sum + (size_t)bk * D + lane, xv);
    if (lane == 0) {
        out_ind[q] = (float)bk;
        atomicAdd(counts + bk, 1.0f);
    }
}

// ---------- single fused EMA: cluster_size + embed_avg + normalize ----------
__global__ __launch_bounds__(256) void ema_kernel(
    const float* __restrict__ cluster_size, const float* __restrict__ embed_avg,
    const float* __restrict__ cs_sum, float* __restrict__ ncs,
    float* __restrict__ nea, float* __restrict__ enorm, int K, int n)
{
    int gid = blockIdx.x * blockDim.x + threadIdx.x;
    if (gid >= K * D) return;
    int k = gid >> 6;
    float total = DECAYF * cs_sum[0] + OMDF * (float)n;
    float cnew  = cluster_size[k] * DECAYF + ncs[k] * OMDF;
    if ((gid & 63) == 0) ncs[k] = cnew;
    float v = embed_avg[gid] * DECAYF + nea[gid] * OMDF;
    nea[gid] = v;
    float smoothed = (cnew + EPSF) / (total + (float)K * EPSF) * total;
    enorm[gid] = v / smoothed;
}

extern "C" void kernel_launch(void* const* d_in, const int* in_sizes, int n_in,
                              void* d_out, int out_size, void* d_ws, size_t ws_size,
                              hipStream_t stream) {
    const float* x            = (const float*)d_in[0];   // [n, 64]
    const float* emb          = (const float*)d_in[1];   // [K, 64]
    const float* cluster_size = (const float*)d_in[2];   // [K]
    const float* embed_avg    = (const float*)d_in[3];   // [K, 64]

    const int n = in_sizes[0] / D;   // 16384
    const int K = in_sizes[1] / D;   // 8192

    // output layout (fp32): quantize | embed_ind | embed_normalized | new_cluster_size | new_embed_avg
    float* out     = (float*)d_out;
    float* quant   = out;                        // n*D
    float* out_ind = quant + (size_t)n * D;      // n
    float* enorm   = out_ind + n;                // K*D  (scratch for eh2 until ema)
    float* ncs     = enorm + (size_t)K * D;      // K    (counts, then EMA'd in place)
    float* nea     = ncs + K;                    // K*D  (embed_sum, then EMA'd in place)

    f16* eh2 = reinterpret_cast<f16*>(enorm);    // K*D f16, fragment-major

    // workspace: e2 | pidx[NLIST][n] | cs_sum
    float* e2     = (float*)d_ws;                        // K
    int*   pidx   = (int*)(e2 + K);                      // NLIST*n
    float* cs_sum = (float*)(pidx + (size_t)NLIST * n);  // 1

    hipMemsetAsync(cs_sum, 0, sizeof(float), stream);

    prep_kernel<<<K * 8 / 512, 512, 0, stream>>>(
        emb, cluster_size, eh2, e2, cs_sum, ncs, nea, K);
    argmin_kernel<<<(n / BM) * NCHUNK, 512, 0, stream>>>(x, eh2, e2, pidx, n, K);
    rerank_kernel<<<(n * 64 + 255) / 256, 256, 0, stream>>>(
        x, emb, e2, pidx, out_ind, quant, nea, ncs, n);
    ema_kernel<<<(K * D + 255) / 256, 256, 0, stream>>>(
        cluster_size, embed_avg, cs_sum, ncs, nea, enorm, K, n);
}

// Round 23
// 72.054 us; speedup vs baseline: 1.4491x; 1.2277x over previous
//
#include <hip/hip_runtime.h>

#define D 64
#define BM 128        // queries per block (4 waves: 2 wm x 2 wn)
#define NCHUNK 4      // K split across blocks (512 blocks = exactly 2/CU, one batch)
#define NLIST (2 * NCHUNK)   // union-top-2 per chunk = 8 lists
#define DECAYF 0.8f
#define OMDF 0.2f
#define EPSF 1e-5f

typedef _Float16 f16;
typedef _Float16 f16x8 __attribute__((ext_vector_type(8)));
typedef float f32x4 __attribute__((ext_vector_type(4)));

// ---------- prep: frag-major f16 split (hi only) + e2 + sum(cluster_size) + zero-init ----
__global__ __launch_bounds__(512) void prep_kernel(
    const float* __restrict__ emb, const float* __restrict__ cluster_size,
    f16* __restrict__ eh2, float* __restrict__ e2,
    float* __restrict__ cs_sum, float* __restrict__ ncs, float* __restrict__ nea,
    int K)
{
    __shared__ float red[512];
    int t = blockIdx.x * 512 + threadIdx.x;
    int lane = t & 63;
    int sub  = (t >> 6) & 7;
    int tile = t >> 9;
    int wn = sub >> 2, nf = (sub >> 1) & 1, ks = sub & 1;
    int lrow = lane & 15, lkg = lane >> 4;
    int k  = tile * 64 + wn * 32 + nf * 16 + lrow;
    int d0 = ks * 32 + lkg * 8;

    // zero accumulation targets (stream order guarantees zero-before-atomics)
    {
        float4 z = {0.f, 0.f, 0.f, 0.f};
        float4* nea4 = reinterpret_cast<float4*>(nea);
        nea4[t]         = z;
        nea4[t + 65536] = z;
        if (t < 2048) reinterpret_cast<float4*>(ncs)[t] = z;
    }

    const float4* p = reinterpret_cast<const float4*>(emb + (size_t)k * D + d0);
    float4 a = p[0], b = p[1];
    float v[8] = {a.x, a.y, a.z, a.w, b.x, b.y, b.z, b.w};
    union { f16 h[8]; uint4 u; } H;
    float part = 0.f;
#pragma unroll
    for (int j = 0; j < 8; ++j) {
        part = fmaf(v[j], v[j], part);
        H.h[j] = (f16)v[j];
    }
    reinterpret_cast<uint4*>(eh2)[t] = H.u;

    red[threadIdx.x] = part;

    if (blockIdx.x < (K >> 9)) {
        float cv = cluster_size[t];
#pragma unroll
        for (int m = 1; m < 64; m <<= 1) cv += __shfl_xor(cv, m, 64);
        if ((threadIdx.x & 63) == 0) atomicAdd(cs_sum, cv);
    }
    __syncthreads();

    if (threadIdx.x < 64) {
        int r = threadIdx.x;
        int rwn = r >> 5, rnf = (r >> 4) & 1, rlr = r & 15;
        float s = 0.f;
#pragma unroll
        for (int kks = 0; kks < 2; ++kks)
#pragma unroll
            for (int g = 0; g < 4; ++g)
                s += red[((rwn * 2 + rnf) * 2 + kks) * 64 + g * 16 + rlr];
        e2[tile * 64 + r] = s;
    }
}

// ---------- MFMA 1-pass f16 capture + top-2 (6-bit tags), union-merged across wn ----------
// r19 structure (proven 56us argmin), NCHUNK=4: 512 blocks = one residency batch.
__global__ __launch_bounds__(256, 2) void argmin_kernel(
    const float* __restrict__ x, const f16* __restrict__ eh2,
    const float* __restrict__ e2, int* __restrict__ pidx, int n, int K)
{
    __shared__ float se2a[2048];          // whole-chunk +0.5*e2 (8KB)
    __shared__ uint4 smerge[2][16][4][2]; // [wm][s][lkg][wn] = {u1, id1, u2, id2} (4KB)

    const int tx   = threadIdx.x;
    const int lane = tx & 63;
    const int wid  = tx >> 6;
    const int wm   = wid >> 1, wn = wid & 1;
    const int lrow = lane & 15;
    const int lkg  = lane >> 4;

    const int chunk = blockIdx.x % NCHUNK;
    const int mblk  = blockIdx.x / NCHUNK;
    const int q0    = mblk * BM;
    const int kc    = K / NCHUNK;    // 2048
    const int k0    = chunk * kc;
    const int gt0   = chunk * (kc / 64);
    const int NT    = kc / 64;       // 32 tiles of 64 codes

    // ---- A fragments (NEGATED f16 hi) + 0.5*f2 per slot ----
    f16x8 ah[4][2];
    f32x4 hf2[4];
#pragma unroll
    for (int m = 0; m < 4; ++m) {
        float f2part = 0.f;
#pragma unroll
        for (int ks = 0; ks < 2; ++ks) {
            int row = q0 + wm * 64 + m * 16 + lrow;
            const float4* p = reinterpret_cast<const float4*>(
                x + (size_t)row * D + ks * 32 + lkg * 8);
            float4 va = p[0], vb = p[1];
            float t[8] = {va.x, va.y, va.z, va.w, vb.x, vb.y, vb.z, vb.w};
#pragma unroll
            for (int j = 0; j < 8; ++j) {
                f2part = fmaf(t[j], t[j], f2part);
                ah[m][ks][j] = (f16)(-t[j]);
            }
        }
        f2part += __shfl_xor(f2part, 16, 64);
        f2part += __shfl_xor(f2part, 32, 64);
#pragma unroll
        for (int r = 0; r < 4; ++r)
            hf2[m][r] = 0.5f * __shfl(f2part, lkg * 4 + r, 64);
    }

    // ---- whole-chunk e2 table, prescaled by +0.5 ----
    for (int i = tx; i < kc; i += 256) se2a[i] = 0.5f * e2[k0 + i];
    __syncthreads();

    // ---- packed top-2 (sorted p1<=p2) per C-slot; 6-bit tag (NT=32) ----
    unsigned int p1[16], p2[16];
#pragma unroll
    for (int s = 0; s < 16; ++s) { p1[s] = 0xFFFFFFFFu; p2[s] = 0xFFFFFFFFu; }

    auto LOADB = [&](f16x8 (&BH)[2][2], int ttv) {
        const f16* bhb = eh2 + ((size_t)(gt0 + ttv) << 12);
#pragma unroll
        for (int nf = 0; nf < 2; ++nf)
#pragma unroll
            for (int ks = 0; ks < 2; ++ks) {
                int sub = (wn * 2 + nf) * 2 + ks;
                BH[nf][ks] = *reinterpret_cast<const f16x8*>(bhb + sub * 512 + lane * 8);
            }
    };

    auto COMPUTE = [&](const f16x8 (&BH)[2][2], int ttv) {
        const float he0 = se2a[ttv * 64 + wn * 32 + lrow];
        const float he1 = se2a[ttv * 64 + wn * 32 + 16 + lrow];
        const unsigned int tagA = (unsigned int)(ttv * 2);
        const unsigned int tagB = tagA + 1u;
#pragma unroll
        for (int m = 0; m < 4; ++m) {
            f32x4 hh0 = hf2[m] + he0;
            f32x4 hh1 = hf2[m] + he1;
            __builtin_amdgcn_s_setprio(1);
            hh0 = __builtin_amdgcn_mfma_f32_16x16x32_f16(ah[m][0], BH[0][0], hh0, 0, 0, 0);
            hh1 = __builtin_amdgcn_mfma_f32_16x16x32_f16(ah[m][0], BH[1][0], hh1, 0, 0, 0);
            hh0 = __builtin_amdgcn_mfma_f32_16x16x32_f16(ah[m][1], BH[0][1], hh0, 0, 0, 0);
            hh1 = __builtin_amdgcn_mfma_f32_16x16x32_f16(ah[m][1], BH[1][1], hh1, 0, 0, 0);
            __builtin_amdgcn_s_setprio(0);
#pragma unroll
            for (int r = 0; r < 4; ++r) {
                unsigned int uA = (__float_as_uint(hh0[r]) & 0xFFFFFFC0u) | tagA;
                unsigned int uB = (__float_as_uint(hh1[r]) & 0xFFFFFFC0u) | tagB;
                unsigned int lo = uA < uB ? uA : uB;
                unsigned int hi = uA < uB ? uB : uA;
                int s = m * 4 + r;
                unsigned int t1 = p1[s], t2 = p2[s];
                unsigned int mx = t1 > lo ? t1 : lo;
                unsigned int mn2 = t2 < hi ? t2 : hi;
                p1[s] = t1 < lo ? t1 : lo;
                p2[s] = mx < mn2 ? mx : mn2;
            }
        }
    };

    // ---- 2-stage register pipeline: load(t+1) overlaps compute(t) ----
    f16x8 bh[2][2], nh[2][2];
    LOADB(bh, 0);
#pragma unroll 1
    for (int tt = 0; tt < NT; tt += 2) {
        LOADB(nh, tt + 1);               // NT even: tt+1 < NT always
        COMPUTE(bh, tt);
        if (tt + 2 < NT) LOADB(bh, tt + 2);
        COMPUTE(nh, tt + 1);
    }

    // ---- cross-lane top-2 merge over the 16 col-lanes; stash to LDS ----
#pragma unroll
    for (int s = 0; s < 16; ++s) {
        unsigned int u1 = p1[s], u2 = p2[s];
        unsigned int tg1 = u1 & 63u, tg2 = u2 & 63u;
        int c1 = (int)((tg1 >> 1) << 6) | (int)((tg1 & 1u) << 4) | (wn << 5) | lrow;
        int c2 = (int)((tg2 >> 1) << 6) | (int)((tg2 & 1u) << 4) | (wn << 5) | lrow;
#pragma unroll
        for (int xm = 1; xm < 16; xm <<= 1) {
            unsigned int o1 = __shfl_xor(u1, xm, 64);
            unsigned int o2 = __shfl_xor(u2, xm, 64);
            int oc1 = __shfl_xor(c1, xm, 64);
            int oc2 = __shfl_xor(c2, xm, 64);
            bool a = o1 < u1 || (o1 == u1 && oc1 < c1);
            unsigned int w1 = a ? o1 : u1;  int wc1 = a ? oc1 : c1;
            unsigned int l1 = a ? u1 : o1;  int lc1 = a ? c1 : oc1;
            bool b = o2 < u2 || (o2 == u2 && oc2 < c2);
            unsigned int m2 = b ? o2 : u2;  int mc2 = b ? oc2 : c2;
            bool cgt = m2 < l1 || (m2 == l1 && mc2 < lc1);
            u1 = w1; c1 = wc1;
            u2 = cgt ? m2 : l1; c2 = cgt ? mc2 : lc1;
        }
        if (lrow == 0) {
            uint4 rec;
            rec.x = u1; rec.y = (unsigned int)(k0 + c1);
            rec.z = u2; rec.w = (unsigned int)(k0 + c2);
            smerge[wm][s][lkg][wn] = rec;
        }
    }
    __syncthreads();

    // ---- union-merge the two wn halves (exact top-2 of the chunk) ----
    if (wn == 0 && lrow == 0) {
#pragma unroll
        for (int s = 0; s < 16; ++s) {
            uint4 A = smerge[wm][s][lkg][0];
            uint4 B = smerge[wm][s][lkg][1];
            bool afirst = A.x < B.x || (A.x == B.x && A.y < B.y);
            unsigned int w1i = afirst ? A.y : B.y;
            unsigned int sAu = afirst ? A.z : B.z;  unsigned int sAi = afirst ? A.w : B.w;
            unsigned int sBu = afirst ? B.x : A.x;  unsigned int sBi = afirst ? B.y : A.y;
            bool c2nd = sAu < sBu || (sAu == sBu && sAi < sBi);
            unsigned int w2i = c2nd ? sAi : sBi;
            int m = s >> 2, r = s & 3;
            int row = q0 + wm * 64 + m * 16 + lkg * 4 + r;
            pidx[(size_t)(chunk * 2)     * n + row] = (int)w1i;
            pidx[(size_t)(chunk * 2 + 1) * n + row] = (int)w2i;
        }
    }
}

// ---------- fused exact re-rank + quantize + scatter: wave/query, 8 lanes/candidate ----
// 8 candidates x 8 lanes: per load instr each candidate's 8 lanes cover a
// contiguous 128B slice (8 segments/instr x 2 instrs -- minimal gather).
__global__ __launch_bounds__(256) void rerank_kernel(
    const float* __restrict__ x, const float* __restrict__ emb, const float* __restrict__ e2,
    const int* __restrict__ pidx, float* __restrict__ out_ind, float* __restrict__ quant,
    float* __restrict__ embed_sum, float* __restrict__ counts, int n)
{
    int gid  = blockIdx.x * blockDim.x + threadIdx.x;
    int q    = gid >> 6;
    int lane = gid & 63;
    int c    = lane >> 3;     // candidate 0..7
    int j    = lane & 7;      // eighth of the row
    if (q >= n) return;

    int k = pidx[(size_t)c * n + q];
    const float4* ep = reinterpret_cast<const float4*>(emb + (size_t)k * D);
    const float4* xp = reinterpret_cast<const float4*>(x + (size_t)q * D);

    float a0 = 0.f, a1 = 0.f, a2 = 0.f, a3 = 0.f;
#pragma unroll
    for (int i = 0; i < 2; ++i) {
        float4 e4 = ep[j + 8 * i];          // contiguous 128B per candidate per instr
        float4 x4 = xp[j + 8 * i];
        a0 = fmaf(x4.x, e4.x, a0);
        a1 = fmaf(x4.y, e4.y, a1);
        a2 = fmaf(x4.z, e4.z, a2);
        a3 = fmaf(x4.w, e4.w, a3);
    }
    float p = (a0 + a1) + (a2 + a3);
    p += __shfl_xor(p, 1, 64);
    p += __shfl_xor(p, 2, 64);
    p += __shfl_xor(p, 4, 64);
    float dist = fmaf(p, -2.0f, e2[k]);
    int   bk   = k;

#pragma unroll
    for (int xm = 8; xm < 64; xm <<= 1) {
        float od = __shfl_xor(dist, xm, 64);
        int   ok = __shfl_xor(bk, xm, 64);
        if (od < dist || (od == dist && ok < bk)) { dist = od; bk = ok; }
    }

    float xv = x[(size_t)q * D + lane];
    quant[(size_t)q * D + lane] = emb[(size_t)bk * D + lane];
    atomicAdd(embed_sum + (size_t)bk * D + lane, xv);
    if (lane == 0) {
        out_ind[q] = (float)bk;
        atomicAdd(counts + bk, 1.0f);
    }
}

// ---------- single fused EMA: cluster_size + embed_avg + normalize ----------
__global__ __launch_bounds__(256) void ema_kernel(
    const float* __restrict__ cluster_size, const float* __restrict__ embed_avg,
    const float* __restrict__ cs_sum, float* __restrict__ ncs,
    float* __restrict__ nea, float* __restrict__ enorm, int K, int n)
{
    int gid = blockIdx.x * blockDim.x + threadIdx.x;
    if (gid >= K * D) return;
    int k = gid >> 6;
    float total = DECAYF * cs_sum[0] + OMDF * (float)n;
    float cnew  = cluster_size[k] * DECAYF + ncs[k] * OMDF;
    if ((gid & 63) == 0) ncs[k] = cnew;
    float v = embed_avg[gid] * DECAYF + nea[gid] * OMDF;
    nea[gid] = v;
    float smoothed = (cnew + EPSF) / (total + (float)K * EPSF) * total;
    enorm[gid] = v / smoothed;
}

extern "C" void kernel_launch(void* const* d_in, const int* in_sizes, int n_in,
                              void* d_out, int out_size, void* d_ws, size_t ws_size,
                              hipStream_t stream) {
    const float* x            = (const float*)d_in[0];   // [n, 64]
    const float* emb          = (const float*)d_in[1];   // [K, 64]
    const float* cluster_size = (const float*)d_in[2];   // [K]
    const float* embed_avg    = (const float*)d_in[3];   // [K, 64]

    const int n = in_sizes[0] / D;   // 16384
    const int K = in_sizes[1] / D;   // 8192

    // output layout (fp32): quantize | embed_ind | embed_normalized | new_cluster_size | new_embed_avg
    float* out     = (float*)d_out;
    float* quant   = out;                        // n*D
    float* out_ind = quant + (size_t)n * D;      // n
    float* enorm   = out_ind + n;                // K*D  (scratch for eh2 until ema)
    float* ncs     = enorm + (size_t)K * D;      // K    (counts, then EMA'd in place)
    float* nea     = ncs + K;                    // K*D  (embed_sum, then EMA'd in place)

    f16* eh2 = reinterpret_cast<f16*>(enorm);    // K*D f16, fragment-major

    // workspace: e2 | pidx[NLIST][n] | cs_sum
    float* e2     = (float*)d_ws;                        // K
    int*   pidx   = (int*)(e2 + K);                      // NLIST*n
    float* cs_sum = (float*)(pidx + (size_t)NLIST * n);  // 1

    hipMemsetAsync(cs_sum, 0, sizeof(float), stream);

    prep_kernel<<<K * 8 / 512, 512, 0, stream>>>(
        emb, cluster_size, eh2, e2, cs_sum, ncs, nea, K);
    argmin_kernel<<<(n / BM) * NCHUNK, 256, 0, stream>>>(x, eh2, e2, pidx, n, K);
    rerank_kernel<<<(n * 64 + 255) / 256, 256, 0, stream>>>(
        x, emb, e2, pidx, out_ind, quant, nea, ncs, n);
    ema_kernel<<<(K * D + 255) / 256, 256, 0, stream>>>(
        cluster_size, embed_avg, cs_sum, ncs, nea, enorm, K, n);
}

// Round 24
// 71.445 us; speedup vs baseline: 1.4615x; 1.0085x over previous
//
#include <hip/hip_runtime.h>

#define D 64
#define BM 128        // queries per block (4 waves: 2 wm x 2 wn)
#define NCHUNK 4      // K split across blocks (512 blocks = 2/CU, one batch)
#define NLIST (2 * NCHUNK)   // union-top-2 per chunk = 8 lists
#define DECAYF 0.8f
#define OMDF 0.2f
#define EPSF 1e-5f

typedef _Float16 f16;
typedef _Float16 f16x8 __attribute__((ext_vector_type(8)));
typedef float f32x4 __attribute__((ext_vector_type(4)));

// ---------- prep: frag-major f16 split (hi only) + e2 + sum(cluster_size) + zero-init ----
__global__ __launch_bounds__(512) void prep_kernel(
    const float* __restrict__ emb, const float* __restrict__ cluster_size,
    f16* __restrict__ eh2, float* __restrict__ e2,
    float* __restrict__ cs_sum, float* __restrict__ ncs, float* __restrict__ nea,
    int K)
{
    __shared__ float red[512];
    int t = blockIdx.x * 512 + threadIdx.x;
    int lane = t & 63;
    int sub  = (t >> 6) & 7;
    int tile = t >> 9;
    int wn = sub >> 2, nf = (sub >> 1) & 1, ks = sub & 1;
    int lrow = lane & 15, lkg = lane >> 4;
    int k  = tile * 64 + wn * 32 + nf * 16 + lrow;
    int d0 = ks * 32 + lkg * 8;

    // zero accumulation targets (stream order guarantees zero-before-atomics)
    {
        float4 z = {0.f, 0.f, 0.f, 0.f};
        float4* nea4 = reinterpret_cast<float4*>(nea);
        nea4[t]         = z;
        nea4[t + 65536] = z;
        if (t < 2048) reinterpret_cast<float4*>(ncs)[t] = z;
    }

    const float4* p = reinterpret_cast<const float4*>(emb + (size_t)k * D + d0);
    float4 a = p[0], b = p[1];
    float v[8] = {a.x, a.y, a.z, a.w, b.x, b.y, b.z, b.w};
    union { f16 h[8]; uint4 u; } H;
    float part = 0.f;
#pragma unroll
    for (int j = 0; j < 8; ++j) {
        part = fmaf(v[j], v[j], part);
        H.h[j] = (f16)v[j];
    }
    reinterpret_cast<uint4*>(eh2)[t] = H.u;

    red[threadIdx.x] = part;

    if (blockIdx.x < (K >> 9)) {
        float cv = cluster_size[t];
#pragma unroll
        for (int m = 1; m < 64; m <<= 1) cv += __shfl_xor(cv, m, 64);
        if ((threadIdx.x & 63) == 0) atomicAdd(cs_sum, cv);
    }
    __syncthreads();

    if (threadIdx.x < 64) {
        int r = threadIdx.x;
        int rwn = r >> 5, rnf = (r >> 4) & 1, rlr = r & 15;
        float s = 0.f;
#pragma unroll
        for (int kks = 0; kks < 2; ++kks)
#pragma unroll
            for (int g = 0; g < 4; ++g)
                s += red[((rwn * 2 + rnf) * 2 + kks) * 64 + g * 16 + rlr];
        e2[tile * 64 + r] = s;
    }
}

// ---------- MFMA 1-pass f16 capture + top-2 (6-bit tags), union-merged across wn ----------
// r23 structure (49us argmin) + depth-2 B prefetch: 3 buffer sets of 16 VGPR each
// (affordable now -- r15's spill was 64-VGPR sets on the 3-pass kernel).
__global__ __launch_bounds__(256, 2) void argmin_kernel(
    const float* __restrict__ x, const f16* __restrict__ eh2,
    const float* __restrict__ e2, int* __restrict__ pidx, int n, int K)
{
    __shared__ float se2a[2048];          // whole-chunk +0.5*e2 (8KB)
    __shared__ uint4 smerge[2][16][4][2]; // [wm][s][lkg][wn] = {u1, id1, u2, id2} (4KB)

    const int tx   = threadIdx.x;
    const int lane = tx & 63;
    const int wid  = tx >> 6;
    const int wm   = wid >> 1, wn = wid & 1;
    const int lrow = lane & 15;
    const int lkg  = lane >> 4;

    const int chunk = blockIdx.x % NCHUNK;
    const int mblk  = blockIdx.x / NCHUNK;
    const int q0    = mblk * BM;
    const int kc    = K / NCHUNK;    // 2048
    const int k0    = chunk * kc;
    const int gt0   = chunk * (kc / 64);
    const int NT    = kc / 64;       // 32 tiles of 64 codes (NT % 3 == 2)

    // ---- A fragments (NEGATED f16 hi) + 0.5*f2 per slot ----
    f16x8 ah[4][2];
    f32x4 hf2[4];
#pragma unroll
    for (int m = 0; m < 4; ++m) {
        float f2part = 0.f;
#pragma unroll
        for (int ks = 0; ks < 2; ++ks) {
            int row = q0 + wm * 64 + m * 16 + lrow;
            const float4* p = reinterpret_cast<const float4*>(
                x + (size_t)row * D + ks * 32 + lkg * 8);
            float4 va = p[0], vb = p[1];
            float t[8] = {va.x, va.y, va.z, va.w, vb.x, vb.y, vb.z, vb.w};
#pragma unroll
            for (int j = 0; j < 8; ++j) {
                f2part = fmaf(t[j], t[j], f2part);
                ah[m][ks][j] = (f16)(-t[j]);
            }
        }
        f2part += __shfl_xor(f2part, 16, 64);
        f2part += __shfl_xor(f2part, 32, 64);
#pragma unroll
        for (int r = 0; r < 4; ++r)
            hf2[m][r] = 0.5f * __shfl(f2part, lkg * 4 + r, 64);
    }

    // ---- whole-chunk e2 table, prescaled by +0.5 ----
    for (int i = tx; i < kc; i += 256) se2a[i] = 0.5f * e2[k0 + i];
    __syncthreads();

    // ---- packed top-2 (sorted p1<=p2) per C-slot; 6-bit tag (NT=32) ----
    unsigned int p1[16], p2[16];
#pragma unroll
    for (int s = 0; s < 16; ++s) { p1[s] = 0xFFFFFFFFu; p2[s] = 0xFFFFFFFFu; }

    auto LOADB = [&](f16x8 (&BH)[2][2], int ttv) {
        const f16* bhb = eh2 + ((size_t)(gt0 + ttv) << 12);
#pragma unroll
        for (int nf = 0; nf < 2; ++nf)
#pragma unroll
            for (int ks = 0; ks < 2; ++ks) {
                int sub = (wn * 2 + nf) * 2 + ks;
                BH[nf][ks] = *reinterpret_cast<const f16x8*>(bhb + sub * 512 + lane * 8);
            }
    };

    auto COMPUTE = [&](const f16x8 (&BH)[2][2], int ttv) {
        const float he0 = se2a[ttv * 64 + wn * 32 + lrow];
        const float he1 = se2a[ttv * 64 + wn * 32 + 16 + lrow];
        const unsigned int tagA = (unsigned int)(ttv * 2);
        const unsigned int tagB = tagA + 1u;
#pragma unroll
        for (int m = 0; m < 4; ++m) {
            f32x4 hh0 = hf2[m] + he0;
            f32x4 hh1 = hf2[m] + he1;
            __builtin_amdgcn_s_setprio(1);
            hh0 = __builtin_amdgcn_mfma_f32_16x16x32_f16(ah[m][0], BH[0][0], hh0, 0, 0, 0);
            hh1 = __builtin_amdgcn_mfma_f32_16x16x32_f16(ah[m][0], BH[1][0], hh1, 0, 0, 0);
            hh0 = __builtin_amdgcn_mfma_f32_16x16x32_f16(ah[m][1], BH[0][1], hh0, 0, 0, 0);
            hh1 = __builtin_amdgcn_mfma_f32_16x16x32_f16(ah[m][1], BH[1][1], hh1, 0, 0, 0);
            __builtin_amdgcn_s_setprio(0);
#pragma unroll
            for (int r = 0; r < 4; ++r) {
                unsigned int uA = (__float_as_uint(hh0[r]) & 0xFFFFFFC0u) | tagA;
                unsigned int uB = (__float_as_uint(hh1[r]) & 0xFFFFFFC0u) | tagB;
                unsigned int lo = uA < uB ? uA : uB;
                unsigned int hi = uA < uB ? uB : uA;
                int s = m * 4 + r;
                unsigned int t1 = p1[s], t2 = p2[s];
                unsigned int mx = t1 > lo ? t1 : lo;
                unsigned int mn2 = t2 < hi ? t2 : hi;
                p1[s] = t1 < lo ? t1 : lo;
                p2[s] = mx < mn2 ? mx : mn2;
            }
        }
    };

    // ---- 3-buffer register pipeline, prefetch depth 2 (NT % 3 == 2) ----
    f16x8 b0[2][2], b1[2][2], b2[2][2];
    LOADB(b0, 0);
    LOADB(b1, 1);
#pragma unroll 1
    for (int tt = 0; tt + 2 < NT; tt += 3) {
        LOADB(b2, tt + 2);
        COMPUTE(b0, tt);
        if (tt + 3 < NT) LOADB(b0, tt + 3);
        COMPUTE(b1, tt + 1);
        if (tt + 4 < NT) LOADB(b1, tt + 4);
        COMPUTE(b2, tt + 2);
    }
    COMPUTE(b0, NT - 2);     // NT%3==2: tail tiles sit in b0, b1
    COMPUTE(b1, NT - 1);

    // ---- cross-lane top-2 merge over the 16 col-lanes; stash to LDS ----
#pragma unroll
    for (int s = 0; s < 16; ++s) {
        unsigned int u1 = p1[s], u2 = p2[s];
        unsigned int tg1 = u1 & 63u, tg2 = u2 & 63u;
        int c1 = (int)((tg1 >> 1) << 6) | (int)((tg1 & 1u) << 4) | (wn << 5) | lrow;
        int c2 = (int)((tg2 >> 1) << 6) | (int)((tg2 & 1u) << 4) | (wn << 5) | lrow;
#pragma unroll
        for (int xm = 1; xm < 16; xm <<= 1) {
            unsigned int o1 = __shfl_xor(u1, xm, 64);
            unsigned int o2 = __shfl_xor(u2, xm, 64);
            int oc1 = __shfl_xor(c1, xm, 64);
            int oc2 = __shfl_xor(c2, xm, 64);
            bool a = o1 < u1 || (o1 == u1 && oc1 < c1);
            unsigned int w1 = a ? o1 : u1;  int wc1 = a ? oc1 : c1;
            unsigned int l1 = a ? u1 : o1;  int lc1 = a ? c1 : oc1;
            bool b = o2 < u2 || (o2 == u2 && oc2 < c2);
            unsigned int m2 = b ? o2 : u2;  int mc2 = b ? oc2 : c2;
            bool cgt = m2 < l1 || (m2 == l1 && mc2 < lc1);
            u1 = w1; c1 = wc1;
            u2 = cgt ? m2 : l1; c2 = cgt ? mc2 : lc1;
        }
        if (lrow == 0) {
            uint4 rec;
            rec.x = u1; rec.y = (unsigned int)(k0 + c1);
            rec.z = u2; rec.w = (unsigned int)(k0 + c2);
            smerge[wm][s][lkg][wn] = rec;
        }
    }
    __syncthreads();

    // ---- union-merge the two wn halves (exact top-2 of the chunk) ----
    if (wn == 0 && lrow == 0) {
#pragma unroll
        for (int s = 0; s < 16; ++s) {
            uint4 A = smerge[wm][s][lkg][0];
            uint4 B = smerge[wm][s][lkg][1];
            bool afirst = A.x < B.x || (A.x == B.x && A.y < B.y);
            unsigned int w1i = afirst ? A.y : B.y;
            unsigned int sAu = afirst ? A.z : B.z;  unsigned int sAi = afirst ? A.w : B.w;
            unsigned int sBu = afirst ? B.x : A.x;  unsigned int sBi = afirst ? B.y : A.y;
            bool c2nd = sAu < sBu || (sAu == sBu && sAi < sBi);
            unsigned int w2i = c2nd ? sAi : sBi;
            int m = s >> 2, r = s & 3;
            int row = q0 + wm * 64 + m * 16 + lkg * 4 + r;
            pidx[(size_t)(chunk * 2)     * n + row] = (int)w1i;
            pidx[(size_t)(chunk * 2 + 1) * n + row] = (int)w2i;
        }
    }
}

// ---------- fused exact re-rank + quantize + scatter: wave/query, 8 lanes/candidate ----
__global__ __launch_bounds__(256) void rerank_kernel(
    const float* __restrict__ x, const float* __restrict__ emb, const float* __restrict__ e2,
    const int* __restrict__ pidx, float* __restrict__ out_ind, float* __restrict__ quant,
    float* __restrict__ embed_sum, float* __restrict__ counts, int n)
{
    int gid  = blockIdx.x * blockDim.x + threadIdx.x;
    int q    = gid >> 6;
    int lane = gid & 63;
    int c    = lane >> 3;     // candidate 0..7
    int j    = lane & 7;      // eighth of the row
    if (q >= n) return;

    int k = pidx[(size_t)c * n + q];
    const float4* ep = reinterpret_cast<const float4*>(emb + (size_t)k * D);
    const float4* xp = reinterpret_cast<const float4*>(x + (size_t)q * D);

    float a0 = 0.f, a1 = 0.f, a2 = 0.f, a3 = 0.f;
#pragma unroll
    for (int i = 0; i < 2; ++i) {
        float4 e4 = ep[j + 8 * i];          // contiguous 128B per candidate per instr
        float4 x4 = xp[j + 8 * i];
        a0 = fmaf(x4.x, e4.x, a0);
        a1 = fmaf(x4.y, e4.y, a1);
        a2 = fmaf(x4.z, e4.z, a2);
        a3 = fmaf(x4.w, e4.w, a3);
    }
    float p = (a0 + a1) + (a2 + a3);
    p += __shfl_xor(p, 1, 64);
    p += __shfl_xor(p, 2, 64);
    p += __shfl_xor(p, 4, 64);
    float dist = fmaf(p, -2.0f, e2[k]);
    int   bk   = k;

#pragma unroll
    for (int xm = 8; xm < 64; xm <<= 1) {
        float od = __shfl_xor(dist, xm, 64);
        int   ok = __shfl_xor(bk, xm, 64);
        if (od < dist || (od == dist && ok < bk)) { dist = od; bk = ok; }
    }

    float xv = x[(size_t)q * D + lane];
    quant[(size_t)q * D + lane] = emb[(size_t)bk * D + lane];
    atomicAdd(embed_sum + (size_t)bk * D + lane, xv);
    if (lane == 0) {
        out_ind[q] = (float)bk;
        atomicAdd(counts + bk, 1.0f);
    }
}

// ---------- single fused EMA: cluster_size + embed_avg + normalize ----------
__global__ __launch_bounds__(256) void ema_kernel(
    const float* __restrict__ cluster_size, const float* __restrict__ embed_avg,
    const float* __restrict__ cs_sum, float* __restrict__ ncs,
    float* __restrict__ nea, float* __restrict__ enorm, int K, int n)
{
    int gid = blockIdx.x * blockDim.x + threadIdx.x;
    if (gid >= K * D) return;
    int k = gid >> 6;
    float total = DECAYF * cs_sum[0] + OMDF * (float)n;
    float cnew  = cluster_size[k] * DECAYF + ncs[k] * OMDF;
    if ((gid & 63) == 0) ncs[k] = cnew;
    float v = embed_avg[gid] * DECAYF + nea[gid] * OMDF;
    nea[gid] = v;
    float smoothed = (cnew + EPSF) / (total + (float)K * EPSF) * total;
    enorm[gid] = v / smoothed;
}

extern "C" void kernel_launch(void* const* d_in, const int* in_sizes, int n_in,
                              void* d_out, int out_size, void* d_ws, size_t ws_size,
                              hipStream_t stream) {
    const float* x            = (const float*)d_in[0];   // [n, 64]
    const float* emb          = (const float*)d_in[1];   // [K, 64]
    const float* cluster_size = (const float*)d_in[2];   // [K]
    const float* embed_avg    = (const float*)d_in[3];   // [K, 64]

    const int n = in_sizes[0] / D;   // 16384
    const int K = in_sizes[1] / D;   // 8192

    // output layout (fp32): quantize | embed_ind | embed_normalized | new_cluster_size | new_embed_avg
    float* out     = (float*)d_out;
    float* quant   = out;                        // n*D
    float* out_ind = quant + (size_t)n * D;      // n
    float* enorm   = out_ind + n;                // K*D  (scratch for eh2 until ema)
    float* ncs     = enorm + (size_t)K * D;      // K    (counts, then EMA'd in place)
    float* nea     = ncs + K;                    // K*D  (embed_sum, then EMA'd in place)

    f16* eh2 = reinterpret_cast<f16*>(enorm);    // K*D f16, fragment-major

    // workspace: e2 | pidx[NLIST][n] | cs_sum
    float* e2     = (float*)d_ws;                        // K
    int*   pidx   = (int*)(e2 + K);                      // NLIST*n
    float* cs_sum = (float*)(pidx + (size_t)NLIST * n);  // 1

    hipMemsetAsync(cs_sum, 0, sizeof(float), stream);

    prep_kernel<<<K * 8 / 512, 512, 0, stream>>>(
        emb, cluster_size, eh2, e2, cs_sum, ncs, nea, K);
    argmin_kernel<<<(n / BM) * NCHUNK, 256, 0, stream>>>(x, eh2, e2, pidx, n, K);
    rerank_kernel<<<(n * 64 + 255) / 256, 256, 0, stream>>>(
        x, emb, e2, pidx, out_ind, quant, nea, ncs, n);
    ema_kernel<<<(K * D + 255) / 256, 256, 0, stream>>>(
        cluster_size, embed_avg, cs_sum, ncs, nea, enorm, K, n);
}